// Round 1
// baseline (446.034 us; speedup 1.0000x reference)
//
#include <hip/hip_runtime.h>

// Problem constants (from setup_inputs): B=32, K=9, C=3, H=W=256, N_INPUTS=2.
#define BB 32
#define KK 9
#define CC 3
#define HH 256
#define WW 256
#define HW (HH * WW)           // 65536 = 2^16
#define NPIX (BB * HW)         // 2,097,152

// d_out layout (floats), in reference return order:
//  o0 pred      [B,3,H,W]  size P = 6291456
//  o1 m_mask_f  [B,9,H,W]  size M = 18874368
//  o2 1-app_f   [B,1,H,W]  size S = 2097152
//  o3 attn      [B,1,H,W]  size S
//  o4 m_mask_b  [B,9,H,W]  size M
//  o5 1-app_b   [B,1,H,W]  size S
//  o6 1-attn    [B,1,H,W]  size S
#define SZ_P ((size_t)BB * CC * HW)
#define SZ_M ((size_t)BB * KK * HW)
#define SZ_S ((size_t)BB * HW)

__global__ __launch_bounds__(256) void seg_attn_kernel(
    const float* __restrict__ gt_f, const float* __restrict__ gt_b,
    float* __restrict__ out) {
  int idx = blockIdx.x * blockDim.x + threadIdx.x;
  if (idx >= NPIX) return;
  int b  = idx >> 16;
  int hw = idx & (HW - 1);
  int h  = hw >> 8;
  int w  = hw & (WW - 1);

  const float* gf = gt_f + (size_t)b * KK * HW;
  const float* gb = gt_b + (size_t)b * KK * HW;

  float seg_f = 0.f, seg_b = 0.f;
#pragma unroll
  for (int k = 0; k < KK; ++k) {
    int y = h + (k / 3) - 1;
    int x = w + (k % 3) - 1;
    if (y >= 0 && y < HH && x >= 0 && x < WW) {
      int off = k * HW + (y << 8) + x;
      seg_f += gf[off];
      seg_b += gb[off];
    }
  }

  // disappear = relu(seg-1); appear = relu(1-disappear)
  float dis_f = fmaxf(seg_f - 1.f, 0.f);
  float app_f = fmaxf(1.f - dis_f, 0.f);
  float dis_b = fmaxf(seg_b - 1.f, 0.f);
  float app_b = fmaxf(1.f - dis_b, 0.f);
  // clamped seg = 1 - relu(1 - seg)
  float sfc = 1.f - fmaxf(1.f - seg_f, 0.f);
  float sbc = 1.f - fmaxf(1.f - seg_b, 0.f);
  float attn = (sfc + 1e-5f) / (sfc + sbc + 2e-5f);

  float* o_disf   = out + SZ_P + SZ_M;                    // o2
  float* o_attn   = out + SZ_P + SZ_M + SZ_S;             // o3
  float* o_disb   = out + SZ_P + 2 * SZ_M + 2 * SZ_S;     // o5
  float* o_1mattn = out + SZ_P + 2 * SZ_M + 3 * SZ_S;     // o6

  o_disf[idx]   = 1.f - app_f;
  o_attn[idx]   = attn;
  o_disb[idx]   = 1.f - app_b;
  o_1mattn[idx] = 1.f - attn;
}

__global__ __launch_bounds__(256) void pred_kernel(
    const float* __restrict__ im_f, const float* __restrict__ im_b,
    const float* __restrict__ gt_f, const float* __restrict__ gt_b,
    float* __restrict__ out) {
  int idx = blockIdx.x * blockDim.x + threadIdx.x;
  if (idx >= NPIX) return;
  int b  = idx >> 16;
  int hw = idx & (HW - 1);
  int h  = hw >> 8;
  int w  = hw & (WW - 1);

  const float* o_disf = out + SZ_P + SZ_M;
  const float* o_attn = out + SZ_P + SZ_M + SZ_S;
  const float* o_disb = out + SZ_P + 2 * SZ_M + 2 * SZ_S;

  const float* gf  = gt_f + (size_t)b * KK * HW;
  const float* gb  = gt_b + (size_t)b * KK * HW;
  // im_input has 6 channels; reference uses the last 3.
  const float* imf = im_f + ((size_t)b * 6 + 3) * HW;
  const float* imb = im_b + ((size_t)b * 6 + 3) * HW;
  const float* dfb = o_disf + (size_t)b * HW;
  const float* dbb = o_disb + (size_t)b * HW;

  float attn = o_attn[idx];

  float pf0 = 0.f, pf1 = 0.f, pf2 = 0.f;
  float pb0 = 0.f, pb1 = 0.f, pb2 = 0.f;
#pragma unroll
  for (int k = 0; k < KK; ++k) {
    int y = h + (k / 3) - 1;
    int x = w + (k % 3) - 1;
    if (y >= 0 && y < HH && x >= 0 && x < WW) {
      int p = (y << 8) + x;
      float af = 1.f - dfb[p];
      float cf = af * gf[k * HW + p];
      pf0 = fmaf(cf, imf[p], pf0);
      pf1 = fmaf(cf, imf[HW + p], pf1);
      pf2 = fmaf(cf, imf[2 * HW + p], pf2);
      float ab = 1.f - dbb[p];
      float cb = ab * gb[k * HW + p];
      pb0 = fmaf(cb, imb[p], pb0);
      pb1 = fmaf(cb, imb[HW + p], pb1);
      pb2 = fmaf(cb, imb[2 * HW + p], pb2);
    }
  }

  float at2 = 1.f - attn;
  size_t base = (size_t)b * CC * HW + hw;
  out[base]          = attn * pf0 + at2 * pb0;
  out[base + HW]     = attn * pf1 + at2 * pb1;
  out[base + 2 * HW] = attn * pf2 + at2 * pb2;
}

extern "C" void kernel_launch(void* const* d_in, const int* in_sizes, int n_in,
                              void* d_out, int out_size, void* d_ws, size_t ws_size,
                              hipStream_t stream) {
  const float* im_f = (const float*)d_in[0];
  const float* im_b = (const float*)d_in[1];
  // d_in[2] = ones (unused — multiplies masks by 1)
  const float* gt_f = (const float*)d_in[3];
  const float* gt_b = (const float*)d_in[4];
  // d_in[5] = m_kernel (one-hot eye, hardcoded as shifts)
  float* out = (float*)d_out;

  dim3 block(256);
  dim3 grid(NPIX / 256);

  // Mask pass-through outputs: plain D2D copies (graph-capture safe).
  hipMemcpyAsync(out + SZ_P, gt_f, SZ_M * sizeof(float),
                 hipMemcpyDeviceToDevice, stream);
  hipMemcpyAsync(out + SZ_P + SZ_M + 2 * SZ_S, gt_b, SZ_M * sizeof(float),
                 hipMemcpyDeviceToDevice, stream);

  seg_attn_kernel<<<grid, block, 0, stream>>>(gt_f, gt_b, out);
  pred_kernel<<<grid, block, 0, stream>>>(im_f, im_b, gt_f, gt_b, out);
}